// Round 1
// baseline (1979.028 us; speedup 1.0000x reference)
//
#include <hip/hip_runtime.h>
#include <hip/hip_bf16.h>
#include <hip/hip_fp16.h>

// Problem constants (LieMoE): tokens, in_dim, hidden, out_dim, experts, topk
#define N_TOK 8192
#define DIM_D 1024
#define DIM_H 4096
#define DIM_O 1024
#define NEXP  8
#define TOPK  3

typedef _Float16 f16_t;
typedef _Float16 f16x4 __attribute__((ext_vector_type(4)));
typedef _Float16 f16x8 __attribute__((ext_vector_type(8)));
typedef float    floatx4 __attribute__((ext_vector_type(4)));

// ---------------------------------------------------------------------------
// async global -> LDS, 16B per lane. LDS dest must be wave-uniform base;
// HW scatters lane i to base + i*16.
// ---------------------------------------------------------------------------
__device__ __forceinline__ void gld_lds16(const void* g, void* l) {
  __builtin_amdgcn_global_load_lds(
      (__attribute__((address_space(1))) void*)(void*)g,
      (__attribute__((address_space(3))) void*)l, 16, 0, 0);
}

// ---------------------------------------------------------------------------
// Gate: fp32 scores = x @ gate_w + gate_b, softmax over 8 experts, top-3
// (stable argmax, first index wins ties, matching lax.top_k), renormalize.
// One wave per token.
// ---------------------------------------------------------------------------
__global__ __launch_bounds__(256) void gate_kernel(
    const float* __restrict__ x, const float* __restrict__ gw,
    const float* __restrict__ gb, float* __restrict__ wts) {
  const int token = blockIdx.x * 4 + (threadIdx.x >> 6);
  const int lane = threadIdx.x & 63;
  float s[NEXP];
#pragma unroll
  for (int e = 0; e < NEXP; e++) s[e] = 0.f;
  const float* xr = x + (size_t)token * DIM_D;
  for (int d = lane; d < DIM_D; d += 64) {
    const float xv = xr[d];
    const float* g = gw + (size_t)d * NEXP;
#pragma unroll
    for (int e = 0; e < NEXP; e++) s[e] += xv * g[e];
  }
#pragma unroll
  for (int off = 32; off > 0; off >>= 1) {
#pragma unroll
    for (int e = 0; e < NEXP; e++) s[e] += __shfl_xor(s[e], off, 64);
  }
#pragma unroll
  for (int e = 0; e < NEXP; e++) s[e] += gb[e];

  float mx = s[0];
#pragma unroll
  for (int e = 1; e < NEXP; e++) mx = fmaxf(mx, s[e]);
  float p[NEXP];
  float den = 0.f;
#pragma unroll
  for (int e = 0; e < NEXP; e++) { p[e] = expf(s[e] - mx); den += p[e]; }

  bool sel[NEXP];
#pragma unroll
  for (int e = 0; e < NEXP; e++) sel[e] = false;
  for (int k = 0; k < TOPK; k++) {
    int bj = 0;
    float bv = -1e30f;
#pragma unroll
    for (int e = 0; e < NEXP; e++) {
      if (!sel[e] && s[e] > bv) { bv = s[e]; bj = e; }
    }
    sel[bj] = true;
  }
  // w[e] = (p[e]/den) / (sum_sel p/den + 1e-8)  ==  p[e] / (sum_sel p + 1e-8*den)
  float msum = 1e-8f * den;
#pragma unroll
  for (int e = 0; e < NEXP; e++) msum += sel[e] ? p[e] : 0.f;
  const float inv = 1.f / msum;
  if (lane < NEXP) {
    wts[(size_t)token * NEXP + lane] = sel[lane] ? p[lane] * inv : 0.f;
  }
}

// ---------------------------------------------------------------------------
// fp32 -> f16 elementwise (x), 4 elems/thread
// ---------------------------------------------------------------------------
__global__ __launch_bounds__(256) void cvt_f32_f16(
    const float* __restrict__ in, f16_t* __restrict__ out, int n4) {
  const int i = blockIdx.x * 256 + threadIdx.x;
  if (i >= n4) return;
  const float4 v = ((const float4*)in)[i];
  f16x4 o;
  o.x = (f16_t)v.x; o.y = (f16_t)v.y; o.z = (f16_t)v.z; o.w = (f16_t)v.w;
  ((f16x4*)out)[i] = o;
}

// ---------------------------------------------------------------------------
// fp32 [E][R][C] -> f16 [E][C][R] tiled transpose-convert (32x32 via LDS)
// ---------------------------------------------------------------------------
__global__ __launch_bounds__(256) void cvt_transpose(
    const float* __restrict__ in, f16_t* __restrict__ out, int R, int C) {
  __shared__ float tile[32][33];
  const int e = blockIdx.z;
  const int r0 = blockIdx.y * 32, c0 = blockIdx.x * 32;
  const int lc = threadIdx.x & 31, lr0 = threadIdx.x >> 5;
  const float* src = in + (size_t)e * R * C;
#pragma unroll
  for (int i = 0; i < 4; i++) {
    const int rr = lr0 + i * 8;
    tile[rr][lc] = src[(size_t)(r0 + rr) * C + c0 + lc];
  }
  __syncthreads();
  f16_t* dst = out + (size_t)e * C * R;
#pragma unroll
  for (int i = 0; i < 4; i++) {
    const int cc = lr0 + i * 8;
    dst[(size_t)(c0 + cc) * R + r0 + lc] = (f16_t)tile[lc][cc];
  }
}

// ---------------------------------------------------------------------------
// m97-style f16 GEMM: C[M,Ncols] = A[M,K] @ BT[Ncols,K]^T
// 128x128 tile, BK=32, 4 waves (2x2), 16x16x32 MFMA, global_load_lds staging,
// XOR-swizzled k-groups (swizzle applied on the staging SOURCE address since
// the LDS destination of global_load_lds is fixed at base + lane*16).
// EPI 0: relu(acc + bias) -> f16 store (hidden)
// EPI 1: out += wts[row,expert] * (acc + bias)   (fp32 RMW)
// ---------------------------------------------------------------------------
template <int EPI>
__global__ __launch_bounds__(256, 2) void gemm_f16(
    const f16_t* __restrict__ A, const f16_t* __restrict__ BT,
    const float* __restrict__ bias, const float* __restrict__ wts, int expert,
    void* __restrict__ Cout, int M, int Ncols, int K) {
  __shared__ __align__(16) f16_t Asm[128 * 32];
  __shared__ __align__(16) f16_t Bsm[128 * 32];
  const int tid = threadIdx.x;
  const int wave = tid >> 6, lane = tid & 63;
  const int q = lane >> 4, r = lane & 15;
  const int m0 = blockIdx.y * 128, n0 = blockIdx.x * 128;
  const int waveM = (wave >> 1) * 64, waveN = (wave & 1) * 64;

  const floatx4 zero = {0.f, 0.f, 0.f, 0.f};
  floatx4 acc[4][4];
#pragma unroll
  for (int mi = 0; mi < 4; mi++)
#pragma unroll
    for (int ni = 0; ni < 4; ni++) acc[mi][ni] = zero;

  // Staging: tile is 128 rows x 32 k (64B/row = 4 groups of 16B).
  // slot s (16B) -> row = s>>2, dest group = s&3; source k-group XOR-swizzled.
  const int s0 = tid, s1 = tid + 256;
  const int row0 = s0 >> 2, row1 = s1 >> 2;
  const int gs0 = (s0 & 3) ^ ((row0 >> 1) & 3);
  const int gs1 = (s1 & 3) ^ ((row1 >> 1) & 3);
  const f16_t* Ar0 = A + (size_t)(m0 + row0) * K + gs0 * 8;
  const f16_t* Ar1 = A + (size_t)(m0 + row1) * K + gs1 * 8;
  const f16_t* Br0 = BT + (size_t)(n0 + row0) * K + gs0 * 8;
  const f16_t* Br1 = BT + (size_t)(n0 + row1) * K + gs1 * 8;
  f16_t* AsmB0 = &Asm[(wave * 64) * 8];
  f16_t* AsmB1 = &Asm[(256 + wave * 64) * 8];
  f16_t* BsmB0 = &Bsm[(wave * 64) * 8];
  f16_t* BsmB1 = &Bsm[(256 + wave * 64) * 8];

  for (int k0 = 0; k0 < K; k0 += 32) {
    gld_lds16(Ar0 + k0, AsmB0);
    gld_lds16(Ar1 + k0, AsmB1);
    gld_lds16(Br0 + k0, BsmB0);
    gld_lds16(Br1 + k0, BsmB1);
    __syncthreads();  // compiler emits vmcnt(0) drain before s_barrier

    f16x8 af[4], bfr[4];
#pragma unroll
    for (int i = 0; i < 4; i++) {
      const int rowa = waveM + i * 16 + r;
      af[i] = *(const f16x8*)&Asm[rowa * 32 + ((q ^ ((rowa >> 1) & 3)) << 3)];
      const int rowb = waveN + i * 16 + r;
      bfr[i] = *(const f16x8*)&Bsm[rowb * 32 + ((q ^ ((rowb >> 1) & 3)) << 3)];
    }
#pragma unroll
    for (int mi = 0; mi < 4; mi++)
#pragma unroll
      for (int ni = 0; ni < 4; ni++)
        acc[mi][ni] = __builtin_amdgcn_mfma_f32_16x16x32_f16(
            af[mi], bfr[ni], acc[mi][ni], 0, 0, 0);
    __syncthreads();
  }

  // Epilogue. D-layout: col = lane&15, row = (lane>>4)*4 + reg.
  if constexpr (EPI == 0) {
    f16_t* C = (f16_t*)Cout;
#pragma unroll
    for (int mi = 0; mi < 4; mi++)
#pragma unroll
      for (int ni = 0; ni < 4; ni++) {
        const int gcol = n0 + waveN + ni * 16 + r;
        const float bv = bias[gcol];
#pragma unroll
        for (int rr = 0; rr < 4; rr++) {
          const int grow = m0 + waveM + mi * 16 + q * 4 + rr;
          C[(size_t)grow * Ncols + gcol] = (f16_t)fmaxf(acc[mi][ni][rr] + bv, 0.f);
        }
      }
  } else {
    float* C = (float*)Cout;
#pragma unroll
    for (int mi = 0; mi < 4; mi++)
#pragma unroll
      for (int ni = 0; ni < 4; ni++) {
        const int gcol = n0 + waveN + ni * 16 + r;
        const float bv = bias[gcol];
#pragma unroll
        for (int rr = 0; rr < 4; rr++) {
          const int grow = m0 + waveM + mi * 16 + q * 4 + rr;
          const float wgt = wts[(size_t)grow * NEXP + expert];
          C[(size_t)grow * Ncols + gcol] += wgt * (acc[mi][ni][rr] + bv);
        }
      }
  }
}

// ---------------------------------------------------------------------------
// launch
// ---------------------------------------------------------------------------
extern "C" void kernel_launch(void* const* d_in, const int* in_sizes, int n_in,
                              void* d_out, int out_size, void* d_ws, size_t ws_size,
                              hipStream_t stream) {
  const float* x      = (const float*)d_in[0];
  const float* gate_w = (const float*)d_in[1];
  const float* gate_b = (const float*)d_in[2];
  const float* w1     = (const float*)d_in[3];
  const float* b1     = (const float*)d_in[4];
  const float* w2     = (const float*)d_in[5];
  const float* b2     = (const float*)d_in[6];
  float* out = (float*)d_out;

  // workspace layout (bytes)
  char* ws = (char*)d_ws;
  const size_t off_w   = 0;                                         // 8192*8*4   = 256KB
  const size_t off_xb  = off_w   + (size_t)N_TOK * NEXP * 4;        // 16MB
  const size_t off_w1t = off_xb  + (size_t)N_TOK * DIM_D * 2;       // 64MB
  const size_t off_w2t = off_w1t + (size_t)NEXP * DIM_H * DIM_D * 2;// 64MB
  const size_t off_h   = off_w2t + (size_t)NEXP * DIM_O * DIM_H * 2;// 64MB
  float* wts  = (float*)(ws + off_w);
  f16_t* xb   = (f16_t*)(ws + off_xb);
  f16_t* w1t  = (f16_t*)(ws + off_w1t);
  f16_t* w2t  = (f16_t*)(ws + off_w2t);
  f16_t* hbuf = (f16_t*)(ws + off_h);

  hipMemsetAsync(d_out, 0, (size_t)out_size * sizeof(float), stream);

  gate_kernel<<<N_TOK / 4, 256, 0, stream>>>(x, gate_w, gate_b, wts);

  const int n4 = N_TOK * DIM_D / 4;
  cvt_f32_f16<<<(n4 + 255) / 256, 256, 0, stream>>>(x, xb, n4);
  cvt_transpose<<<dim3(DIM_H / 32, DIM_D / 32, NEXP), 256, 0, stream>>>(
      w1, w1t, DIM_D, DIM_H);
  cvt_transpose<<<dim3(DIM_O / 32, DIM_H / 32, NEXP), 256, 0, stream>>>(
      w2, w2t, DIM_H, DIM_O);

  for (int e = 0; e < NEXP; e++) {
    gemm_f16<0><<<dim3(DIM_H / 128, N_TOK / 128), 256, 0, stream>>>(
        xb, w1t + (size_t)e * DIM_H * DIM_D, b1 + (size_t)e * DIM_H,
        nullptr, 0, hbuf, N_TOK, DIM_H, DIM_D);
    gemm_f16<1><<<dim3(DIM_O / 128, N_TOK / 128), 256, 0, stream>>>(
        hbuf, w2t + (size_t)e * DIM_O * DIM_H, b2 + (size_t)e * DIM_O,
        wts, e, out, N_TOK, DIM_O, DIM_H);
  }
}

// Round 2
// 1284.383 us; speedup vs baseline: 1.5408x; 1.5408x over previous
//
#include <hip/hip_runtime.h>
#include <hip/hip_bf16.h>
#include <hip/hip_fp16.h>

// LieMoE: tokens, in_dim, hidden, out_dim, experts, topk
#define N_TOK 8192
#define DIM_D 1024
#define DIM_H 4096
#define DIM_O 1024
#define NEXP  8
#define TOPK  3

// Sparse routing capacity: sum of per-expert counts == N_TOK*TOPK = 24576.
// 128-aligned per-expert padding adds < 8*128 -> 25600 rows, <= 200 m-tiles.
#define CAP_ROWS  25600
#define MAX_TILES 200

typedef _Float16 f16_t;
typedef _Float16 f16x4 __attribute__((ext_vector_type(4)));
typedef _Float16 f16x8 __attribute__((ext_vector_type(8)));
typedef float    floatx4 __attribute__((ext_vector_type(4)));

__device__ __forceinline__ void gld_lds16(const void* g, void* l) {
  __builtin_amdgcn_global_load_lds(
      (__attribute__((address_space(1))) void*)(void*)g,
      (__attribute__((address_space(3))) void*)l, 16, 0, 0);
}

// ---------------------------------------------------------------------------
// Gate: fp32 scores, softmax, top-3 (stable, first-index wins ties),
// renormalize. Also builds per-expert token lists via atomicAdd.
// One wave per token.
// ---------------------------------------------------------------------------
__global__ __launch_bounds__(256) void gate_kernel(
    const float* __restrict__ x, const float* __restrict__ gw,
    const float* __restrict__ gb, float* __restrict__ wts,
    int* __restrict__ lists, int* __restrict__ cnt) {
  const int token = blockIdx.x * 4 + (threadIdx.x >> 6);
  const int lane = threadIdx.x & 63;
  float s[NEXP];
#pragma unroll
  for (int e = 0; e < NEXP; e++) s[e] = 0.f;
  const float* xr = x + (size_t)token * DIM_D;
  for (int d = lane; d < DIM_D; d += 64) {
    const float xv = xr[d];
    const float* g = gw + (size_t)d * NEXP;
#pragma unroll
    for (int e = 0; e < NEXP; e++) s[e] += xv * g[e];
  }
#pragma unroll
  for (int off = 32; off > 0; off >>= 1) {
#pragma unroll
    for (int e = 0; e < NEXP; e++) s[e] += __shfl_xor(s[e], off, 64);
  }
#pragma unroll
  for (int e = 0; e < NEXP; e++) s[e] += gb[e];

  float mx = s[0];
#pragma unroll
  for (int e = 1; e < NEXP; e++) mx = fmaxf(mx, s[e]);
  float p[NEXP];
  float den = 0.f;
#pragma unroll
  for (int e = 0; e < NEXP; e++) { p[e] = expf(s[e] - mx); den += p[e]; }

  bool sel[NEXP];
#pragma unroll
  for (int e = 0; e < NEXP; e++) sel[e] = false;
  for (int k = 0; k < TOPK; k++) {
    int bj = 0;
    float bv = -1e30f;
#pragma unroll
    for (int e = 0; e < NEXP; e++) {
      if (!sel[e] && s[e] > bv) { bv = s[e]; bj = e; }
    }
    sel[bj] = true;
  }
  float msum = 1e-8f * den;
#pragma unroll
  for (int e = 0; e < NEXP; e++) msum += sel[e] ? p[e] : 0.f;
  const float inv = 1.f / msum;
  if (lane < NEXP) {
    wts[(size_t)token * NEXP + lane] = sel[lane] ? p[lane] * inv : 0.f;
  }
  if (lane == 0) {
#pragma unroll
    for (int e = 0; e < NEXP; e++) {
      if (sel[e]) {
        const int pos = atomicAdd(&cnt[e], 1);
        lists[e * N_TOK + pos] = token;
      }
    }
  }
}

// ---------------------------------------------------------------------------
// Plan: aligned prefix sums of counts -> start rows; flat m-tile table.
// Entry: (expert << 16) | (tile_row0 >> 7)
// ---------------------------------------------------------------------------
__global__ void plan_kernel(const int* __restrict__ cnt, int* __restrict__ start,
                            int* __restrict__ table, int* __restrict__ total) {
  if (threadIdx.x == 0) {
    int r0 = 0, t = 0;
    for (int e = 0; e < NEXP; e++) {
      start[e] = r0;
      const int nt = (cnt[e] + 127) >> 7;
      for (int i = 0; i < nt; i++) table[t++] = (e << 16) | ((r0 >> 7) + i);
      r0 += nt << 7;
    }
    total[0] = t;
  }
}

// ---------------------------------------------------------------------------
// Fill compact-row metadata: rowtok (token index or -1 for pad), roww (weight)
// ---------------------------------------------------------------------------
__global__ __launch_bounds__(256) void fill_kernel(
    const int* __restrict__ cnt, const int* __restrict__ start,
    const int* __restrict__ lists, const float* __restrict__ wts,
    int* __restrict__ rowtok, float* __restrict__ roww) {
  const int e = blockIdx.y;
  const int i = blockIdx.x * 256 + threadIdx.x;
  const int c = cnt[e];
  const int pad = (c + 127) & ~127;
  if (i >= pad) return;
  const int r = start[e] + i;
  if (i < c) {
    const int t = lists[e * N_TOK + i];
    rowtok[r] = t;
    roww[r] = wts[(size_t)t * NEXP + e];
  } else {
    rowtok[r] = -1;
    roww[r] = 0.f;
  }
}

// ---------------------------------------------------------------------------
// fp32 -> f16 elementwise (x)
// ---------------------------------------------------------------------------
__global__ __launch_bounds__(256) void cvt_f32_f16(
    const float* __restrict__ in, f16_t* __restrict__ out, int n4) {
  const int i = blockIdx.x * 256 + threadIdx.x;
  if (i >= n4) return;
  const float4 v = ((const float4*)in)[i];
  f16x4 o;
  o.x = (f16_t)v.x; o.y = (f16_t)v.y; o.z = (f16_t)v.z; o.w = (f16_t)v.w;
  ((f16x4*)out)[i] = o;
}

// ---------------------------------------------------------------------------
// fp32 [E][R][C] -> f16 [E][C][R] tiled transpose-convert (32x32 via LDS)
// ---------------------------------------------------------------------------
__global__ __launch_bounds__(256) void cvt_transpose(
    const float* __restrict__ in, f16_t* __restrict__ out, int R, int C) {
  __shared__ float tile[32][33];
  const int e = blockIdx.z;
  const int r0 = blockIdx.y * 32, c0 = blockIdx.x * 32;
  const int lc = threadIdx.x & 31, lr0 = threadIdx.x >> 5;
  const float* src = in + (size_t)e * R * C;
#pragma unroll
  for (int i = 0; i < 4; i++) {
    const int rr = lr0 + i * 8;
    tile[rr][lc] = src[(size_t)(r0 + rr) * C + c0 + lc];
  }
  __syncthreads();
  f16_t* dst = out + (size_t)e * C * R;
#pragma unroll
  for (int i = 0; i < 4; i++) {
    const int cc = lr0 + i * 8;
    dst[(size_t)(c0 + cc) * R + r0 + lc] = (f16_t)tile[lc][cc];
  }
}

// ---------------------------------------------------------------------------
// Merged sparse GEMM1: hg[r, 0..Hc) = relu( x[rowtok[r]] @ W1[e][:, cH..cH+Hc) + b1 )
// 128x128 tile, BK=32, 4 waves, 16x16x32 f16 MFMA, global_load_lds staging,
// XOR-swizzled source k-groups. A rows gathered via rowtok indirection
// (per-lane SOURCE address is fine; only the LDS dest is wave-uniform).
// ---------------------------------------------------------------------------
__global__ __launch_bounds__(256, 2) void gemm1_moe(
    const f16_t* __restrict__ xb, const f16_t* __restrict__ w1t,
    const float* __restrict__ b1, const int* __restrict__ rowtok,
    const int* __restrict__ table, const int* __restrict__ total,
    f16_t* __restrict__ hg, int Hc, int cH) {
  const int mt = blockIdx.y;
  if (mt >= total[0]) return;
  const int ent = table[mt];
  const int e = ent >> 16;
  const int r0 = (ent & 0xffff) << 7;
  const int n0 = blockIdx.x * 128;  // within chunk

  __shared__ __align__(16) f16_t Asm[128 * 32];
  __shared__ __align__(16) f16_t Bsm[128 * 32];
  const int tid = threadIdx.x;
  const int wave = tid >> 6, lane = tid & 63;
  const int q = lane >> 4, r = lane & 15;
  const int waveM = (wave >> 1) * 64, waveN = (wave & 1) * 64;

  const floatx4 zero = {0.f, 0.f, 0.f, 0.f};
  floatx4 acc[4][4];
#pragma unroll
  for (int mi = 0; mi < 4; mi++)
#pragma unroll
    for (int ni = 0; ni < 4; ni++) acc[mi][ni] = zero;

  const f16_t* BT = w1t + (size_t)e * DIM_H * DIM_D + (size_t)cH * DIM_D;

  const int s0 = tid, s1 = tid + 256;
  const int row0 = s0 >> 2, row1 = s1 >> 2;
  const int gs0 = (s0 & 3) ^ ((row0 >> 1) & 3);
  const int gs1 = (s1 & 3) ^ ((row1 >> 1) & 3);
  const int tok0 = max(rowtok[r0 + row0], 0);
  const int tok1 = max(rowtok[r0 + row1], 0);
  const f16_t* Ar0 = xb + (size_t)tok0 * DIM_D + gs0 * 8;
  const f16_t* Ar1 = xb + (size_t)tok1 * DIM_D + gs1 * 8;
  const f16_t* Br0 = BT + (size_t)(n0 + row0) * DIM_D + gs0 * 8;
  const f16_t* Br1 = BT + (size_t)(n0 + row1) * DIM_D + gs1 * 8;
  f16_t* AsmB0 = &Asm[(wave * 64) * 8];
  f16_t* AsmB1 = &Asm[(256 + wave * 64) * 8];
  f16_t* BsmB0 = &Bsm[(wave * 64) * 8];
  f16_t* BsmB1 = &Bsm[(256 + wave * 64) * 8];

  for (int k0 = 0; k0 < DIM_D; k0 += 32) {
    gld_lds16(Ar0 + k0, AsmB0);
    gld_lds16(Ar1 + k0, AsmB1);
    gld_lds16(Br0 + k0, BsmB0);
    gld_lds16(Br1 + k0, BsmB1);
    __syncthreads();
    f16x8 af[4], bfr[4];
#pragma unroll
    for (int i = 0; i < 4; i++) {
      const int rowa = waveM + i * 16 + r;
      af[i] = *(const f16x8*)&Asm[rowa * 32 + ((q ^ ((rowa >> 1) & 3)) << 3)];
      const int rowb = waveN + i * 16 + r;
      bfr[i] = *(const f16x8*)&Bsm[rowb * 32 + ((q ^ ((rowb >> 1) & 3)) << 3)];
    }
#pragma unroll
    for (int mi = 0; mi < 4; mi++)
#pragma unroll
      for (int ni = 0; ni < 4; ni++)
        acc[mi][ni] = __builtin_amdgcn_mfma_f32_16x16x32_f16(
            af[mi], bfr[ni], acc[mi][ni], 0, 0, 0);
    __syncthreads();
  }

  // D-layout: col = lane&15, row = (lane>>4)*4 + reg
#pragma unroll
  for (int mi = 0; mi < 4; mi++)
#pragma unroll
    for (int ni = 0; ni < 4; ni++) {
      const int gcol = n0 + waveN + ni * 16 + r;
      const float bv = b1[(size_t)e * DIM_H + cH + gcol];
#pragma unroll
      for (int rr = 0; rr < 4; rr++) {
        const int grow = r0 + waveM + mi * 16 + q * 4 + rr;
        hg[(size_t)grow * Hc + gcol] = (f16_t)fmaxf(acc[mi][ni][rr] + bv, 0.f);
      }
    }
}

// ---------------------------------------------------------------------------
// Merged sparse GEMM2: out[rowtok[r]] += roww[r] * ( hg[r] @ W2[e][cH.., :] + b2 )
// Scatter via unsafeAtomicAdd (native global_atomic_add_f32).
// ---------------------------------------------------------------------------
__global__ __launch_bounds__(256, 2) void gemm2_moe(
    const f16_t* __restrict__ hg, const f16_t* __restrict__ w2t,
    const float* __restrict__ b2, const int* __restrict__ rowtok,
    const float* __restrict__ roww, const int* __restrict__ table,
    const int* __restrict__ total, float* __restrict__ out, int Hc, int cH,
    int addBias) {
  const int mt = blockIdx.y;
  if (mt >= total[0]) return;
  const int ent = table[mt];
  const int e = ent >> 16;
  const int r0 = (ent & 0xffff) << 7;
  const int n0 = blockIdx.x * 128;  // O cols

  __shared__ __align__(16) f16_t Asm[128 * 32];
  __shared__ __align__(16) f16_t Bsm[128 * 32];
  const int tid = threadIdx.x;
  const int wave = tid >> 6, lane = tid & 63;
  const int q = lane >> 4, r = lane & 15;
  const int waveM = (wave >> 1) * 64, waveN = (wave & 1) * 64;

  const floatx4 zero = {0.f, 0.f, 0.f, 0.f};
  floatx4 acc[4][4];
#pragma unroll
  for (int mi = 0; mi < 4; mi++)
#pragma unroll
    for (int ni = 0; ni < 4; ni++) acc[mi][ni] = zero;

  const f16_t* BT = w2t + (size_t)e * DIM_O * DIM_H + cH;

  const int s0 = tid, s1 = tid + 256;
  const int row0 = s0 >> 2, row1 = s1 >> 2;
  const int gs0 = (s0 & 3) ^ ((row0 >> 1) & 3);
  const int gs1 = (s1 & 3) ^ ((row1 >> 1) & 3);
  const f16_t* Ar0 = hg + (size_t)(r0 + row0) * Hc + gs0 * 8;
  const f16_t* Ar1 = hg + (size_t)(r0 + row1) * Hc + gs1 * 8;
  const f16_t* Br0 = BT + (size_t)(n0 + row0) * DIM_H + gs0 * 8;
  const f16_t* Br1 = BT + (size_t)(n0 + row1) * DIM_H + gs1 * 8;
  f16_t* AsmB0 = &Asm[(wave * 64) * 8];
  f16_t* AsmB1 = &Asm[(256 + wave * 64) * 8];
  f16_t* BsmB0 = &Bsm[(wave * 64) * 8];
  f16_t* BsmB1 = &Bsm[(256 + wave * 64) * 8];

  for (int k0 = 0; k0 < Hc; k0 += 32) {
    gld_lds16(Ar0 + k0, AsmB0);
    gld_lds16(Ar1 + k0, AsmB1);
    gld_lds16(Br0 + k0, BsmB0);
    gld_lds16(Br1 + k0, BsmB1);
    __syncthreads();
    f16x8 af[4], bfr[4];
#pragma unroll
    for (int i = 0; i < 4; i++) {
      const int rowa = waveM + i * 16 + r;
      af[i] = *(const f16x8*)&Asm[rowa * 32 + ((q ^ ((rowa >> 1) & 3)) << 3)];
      const int rowb = waveN + i * 16 + r;
      bfr[i] = *(const f16x8*)&Bsm[rowb * 32 + ((q ^ ((rowb >> 1) & 3)) << 3)];
    }
#pragma unroll
    for (int mi = 0; mi < 4; mi++)
#pragma unroll
      for (int ni = 0; ni < 4; ni++)
        acc[mi][ni] = __builtin_amdgcn_mfma_f32_16x16x32_f16(
            af[mi], bfr[ni], acc[mi][ni], 0, 0, 0);
    __syncthreads();
  }

#pragma unroll
  for (int mi = 0; mi < 4; mi++)
#pragma unroll
    for (int ni = 0; ni < 4; ni++) {
      const int gcol = n0 + waveN + ni * 16 + r;
      const float bv = addBias ? b2[(size_t)e * DIM_O + gcol] : 0.f;
#pragma unroll
      for (int rr = 0; rr < 4; rr++) {
        const int grow = r0 + waveM + mi * 16 + q * 4 + rr;
        const int t = rowtok[grow];
        if (t >= 0) {
          const float w = roww[grow];
          unsafeAtomicAdd(&out[(size_t)t * DIM_O + gcol],
                          w * (acc[mi][ni][rr] + bv));
        }
      }
    }
}

// ---------------------------------------------------------------------------
// launch
// ---------------------------------------------------------------------------
extern "C" void kernel_launch(void* const* d_in, const int* in_sizes, int n_in,
                              void* d_out, int out_size, void* d_ws, size_t ws_size,
                              hipStream_t stream) {
  const float* x      = (const float*)d_in[0];
  const float* gate_w = (const float*)d_in[1];
  const float* gate_b = (const float*)d_in[2];
  const float* w1     = (const float*)d_in[3];
  const float* b1     = (const float*)d_in[4];
  const float* w2     = (const float*)d_in[5];
  const float* b2     = (const float*)d_in[6];
  float* out = (float*)d_out;

  // workspace layout
  char* ws = (char*)d_ws;
  const size_t off_wts    = 0;                        // 256 KB
  const size_t off_lists  = off_wts + 262144;         // 256 KB
  const size_t off_cnt    = off_lists + 262144;       // 512 B
  const size_t off_start  = off_cnt + 512;            // 512 B
  const size_t off_total  = off_start + 512;          // 512 B
  const size_t off_table  = off_total + 512;          // 2 KB
  const size_t off_rowtok = off_table + 2048;         // 100 KB
  const size_t off_roww   = off_rowtok + 102400;      // 100 KB
  const size_t META       = 1 << 20;                  // 1 MB reserved
  const size_t off_w1t = META;                                        // 64 MB
  const size_t off_w2t = off_w1t + (size_t)NEXP * DIM_H * DIM_D * 2;  // 64 MB
  const size_t off_xb  = off_w2t + (size_t)NEXP * DIM_O * DIM_H * 2;  // 16 MB
  const size_t off_hg  = off_xb + (size_t)N_TOK * DIM_D * 2;

  float* wts   = (float*)(ws + off_wts);
  int*   lists = (int*)(ws + off_lists);
  int*   cnt   = (int*)(ws + off_cnt);
  int*   start = (int*)(ws + off_start);
  int*   total = (int*)(ws + off_total);
  int*   table = (int*)(ws + off_table);
  int*   rowtok= (int*)(ws + off_rowtok);
  float* roww  = (float*)(ws + off_roww);
  f16_t* w1t   = (f16_t*)(ws + off_w1t);
  f16_t* w2t   = (f16_t*)(ws + off_w2t);
  f16_t* xb    = (f16_t*)(ws + off_xb);
  f16_t* hg    = (f16_t*)(ws + off_hg);

  // pick largest H-chunk that fits (ws_size constant across calls)
  int Hc = 512;
  for (int cand = 4096; cand >= 512; cand >>= 1) {
    if (off_hg + (size_t)CAP_ROWS * cand * 2 <= ws_size) { Hc = cand; break; }
  }
  const int nchunks = DIM_H / Hc;

  hipMemsetAsync(cnt, 0, 512, stream);
  hipMemsetAsync(d_out, 0, (size_t)out_size * sizeof(float), stream);

  gate_kernel<<<N_TOK / 4, 256, 0, stream>>>(x, gate_w, gate_b, wts, lists, cnt);
  plan_kernel<<<1, 64, 0, stream>>>(cnt, start, table, total);
  fill_kernel<<<dim3(N_TOK / 256, NEXP), 256, 0, stream>>>(
      cnt, start, lists, wts, rowtok, roww);

  const int n4 = N_TOK * DIM_D / 4;
  cvt_f32_f16<<<(n4 + 255) / 256, 256, 0, stream>>>(x, xb, n4);
  cvt_transpose<<<dim3(DIM_H / 32, DIM_D / 32, NEXP), 256, 0, stream>>>(
      w1, w1t, DIM_D, DIM_H);
  cvt_transpose<<<dim3(DIM_O / 32, DIM_H / 32, NEXP), 256, 0, stream>>>(
      w2, w2t, DIM_H, DIM_O);

  for (int c = 0; c < nchunks; c++) {
    const int cH = c * Hc;
    gemm1_moe<<<dim3(Hc / 128, MAX_TILES), 256, 0, stream>>>(
        xb, w1t, b1, rowtok, table, total, hg, Hc, cH);
    gemm2_moe<<<dim3(DIM_O / 128, MAX_TILES), 256, 0, stream>>>(
        hg, w2t, b2, rowtok, roww, table, total, out, Hc, cH, c == 0);
  }
}